// Round 1
// baseline (441.758 us; speedup 1.0000x reference)
//
#include <hip/hip_runtime.h>

typedef _Float16 half8  __attribute__((ext_vector_type(8)));
typedef float    floatx4 __attribute__((ext_vector_type(4)));

#define N_NODES 50000
#define N_EDGES 800000
#define SLOPE 0.05f

// ---- workspace layout (bytes) ----
// z:   fp16 [N_NODES][128]   = x @ W0 (no bias, no activation)
// Wt1: fp16 [128][128]       Wt1[n][k] = W1[k][n]
// Wt2: fp16 [64][128]        Wt2[n][k] = W2[k][n]
// b0,b1,b2: fp32
#define WS_Z   0ull
#define WS_W1  (WS_Z  + (size_t)N_NODES * 128 * 2)
#define WS_W2  (WS_W1 + 128 * 128 * 2)
#define WS_B0  (WS_W2 + 64 * 128 * 2)
#define WS_B1  (WS_B0 + 128 * 4)
#define WS_B2  (WS_B1 + 128 * 4)

#define W0_STRIDE 72    // 64 + 8 fp16 pad
#define H_STRIDE 136    // 128 + 8 fp16 pad
#define HC_STRIDE 40    // 32 + 8 fp16 pad

#define Z_BLOCKS 391            // ceil(50000/128)
#define EDGE_TILES (N_EDGES / 256)   // 3125 tiles of 256 edges
#define EDGE_GRID 512           // 2 blocks/CU, persistent

__device__ __forceinline__ float leaky(float t) { return t >= 0.f ? t : SLOPE * t; }

// ---------------- kernel 1: z = x @ W0 (fp16 out), + one wprep block ----------------
__global__ __launch_bounds__(512, 4) void z_kernel(const float* __restrict__ x,
                                                   const float* __restrict__ W0,
                                                   const float* __restrict__ W1,
                                                   const float* __restrict__ W2,
                                                   const float* __restrict__ b0,
                                                   const float* __restrict__ b1,
                                                   const float* __restrict__ b2,
                                                   unsigned char* __restrict__ ws) {
    __shared__ __align__(16) _Float16 w0t[128 * W0_STRIDE];
    __shared__ __align__(16) _Float16 hbuf[8][16 * H_STRIDE];

    if (blockIdx.x == Z_BLOCKS) {   // extra block: weight transpose + fp16 convert
        _Float16* wt1 = (_Float16*)(ws + WS_W1);
        _Float16* wt2 = (_Float16*)(ws + WS_W2);
        float* B0 = (float*)(ws + WS_B0);
        float* B1 = (float*)(ws + WS_B1);
        float* B2 = (float*)(ws + WS_B2);
        for (int t = threadIdx.x; t < 16384; t += 512) {   // W1 [128][128] -> Wt1[n][k]
            int k = t >> 7, n = t & 127;
            wt1[n * 128 + k] = (_Float16)W1[k * 128 + n];
        }
        for (int t = threadIdx.x; t < 8192; t += 512) {    // W2 [128][64] -> Wt2[n][k]
            int k = t >> 6, n = t & 63;
            wt2[n * 128 + k] = (_Float16)W2[k * 64 + n];
        }
        if (threadIdx.x < 128) B0[threadIdx.x] = b0[threadIdx.x];
        else if (threadIdx.x < 256) B1[threadIdx.x - 128] = b1[threadIdx.x - 128];
        else if (threadIdx.x < 320) B2[threadIdx.x - 256] = b2[threadIdx.x - 256];
        return;
    }

    _Float16* __restrict__ z = (_Float16*)(ws + WS_Z);

    {   // stage W0^T into LDS as fp16: w0t[n][k]
        int t = threadIdx.x;
        int n = t >> 2, k0 = (t & 3) * 16;
        half8 t0, t1;
        #pragma unroll
        for (int j = 0; j < 8; ++j) t0[j] = (_Float16)W0[(k0 + j) * 128 + n];
        #pragma unroll
        for (int j = 0; j < 8; ++j) t1[j] = (_Float16)W0[(k0 + 8 + j) * 128 + n];
        *(half8*)&w0t[n * W0_STRIDE + k0] = t0;
        *(half8*)&w0t[n * W0_STRIDE + k0 + 8] = t1;
    }
    __syncthreads();

    const int wave = threadIdx.x >> 6, lane = threadIdx.x & 63;
    const int cl = lane & 15, q = lane >> 4;
    const int rowbase = blockIdx.x * 128 + wave * 16;
    int row = rowbase + cl; if (row > N_NODES - 1) row = N_NODES - 1;

    // A-frags straight from x rows: A[m=lane&15][k=quad*8+j]
    half8 a[2];
    #pragma unroll
    for (int ks = 0; ks < 2; ++ks) {
        const floatx4* px = (const floatx4*)(x + (size_t)row * 64 + ks * 32 + q * 8);
        floatx4 u0 = px[0], u1 = px[1];
        #pragma unroll
        for (int j = 0; j < 4; ++j) { a[ks][j] = (_Float16)u0[j]; a[ks][4 + j] = (_Float16)u1[j]; }
    }

    _Float16* hs = &hbuf[wave][0];
    #pragma unroll
    for (int n = 0; n < 8; ++n) {
        floatx4 c = {0.f, 0.f, 0.f, 0.f};
        #pragma unroll
        for (int ks = 0; ks < 2; ++ks) {
            half8 b = *(const half8*)&w0t[(n * 16 + cl) * W0_STRIDE + ks * 32 + q * 8];
            c = __builtin_amdgcn_mfma_f32_16x16x32_f16(a[ks], b, c, 0, 0, 0);
        }
        #pragma unroll
        for (int r = 0; r < 4; ++r)   // C/D: col=lane&15, row=quad*4+reg
            hs[(q * 4 + r) * H_STRIDE + n * 16 + cl] = (_Float16)c[r];
    }

    // coalesced LDS slice -> global z
    int rl = lane >> 2, ch = lane & 3;
    int grow = rowbase + rl;
    if (grow < N_NODES) {
        #pragma unroll
        for (int i = 0; i < 4; ++i)
            *(half8*)(z + (size_t)grow * 128 + i * 32 + ch * 8) =
                *(const half8*)&hs[rl * H_STRIDE + i * 32 + ch * 8];
    }
}

// ---------------- kernel 2: persistent per-edge fused MLP (layers 1,2) ----------------
// 512 threads = 8 waves; each wave owns 32 edges per tile (two 16-edge A-frag groups
// sharing every W1/W2 LDS fragment read); 256 edges per block-tile; grid-strided.
__global__ __launch_bounds__(512, 4) void edge_kernel(const int* __restrict__ ei,
                                                      const unsigned char* __restrict__ ws,
                                                      float* __restrict__ out) {
    __shared__ __align__(16) _Float16 w1s[128 * H_STRIDE];        // 34816 B
    __shared__ __align__(16) _Float16 w2s[64 * H_STRIDE];         // 17408 B
    __shared__ __align__(16) _Float16 hc[8][2][16 * HC_STRIDE];   // 20480 B
    __shared__ __align__(16) float b0s[128], b1s[128], b2s[64];   // total 72.3 KB -> 2 blocks/CU

    const _Float16* __restrict__ z    = (const _Float16*)(ws + WS_Z);
    const _Float16* __restrict__ wt1g = (const _Float16*)(ws + WS_W1);
    const _Float16* __restrict__ wt2g = (const _Float16*)(ws + WS_W2);

    const int wave = threadIdx.x >> 6, lane = threadIdx.x & 63;
    const int cl = lane & 15, q = lane >> 4;

    // first tile's edge indices — issued before staging so ei latency hides under it
    int tile = blockIdx.x;
    int s0, d0, s1, d1;
    {
        const int r0 = tile * 256 + wave * 32 + cl;
        s0 = ei[r0];      d0 = ei[N_EDGES + r0];
        s1 = ei[r0 + 16]; d1 = ei[N_EDGES + r0 + 16];
    }

    {   // stage weights into LDS with padded stride — ONCE per persistent block
        int t = threadIdx.x;
        #pragma unroll
        for (int it = 0; it < 4; ++it) {
            int c = t + it * 512;               // 2048 chunks of 8 fp16
            int row = c >> 4, cc = c & 15;
            *(half8*)&w1s[row * H_STRIDE + cc * 8] = *(const half8*)&wt1g[row * 128 + cc * 8];
        }
        #pragma unroll
        for (int it = 0; it < 2; ++it) {
            int c = t + it * 512;               // 1024 chunks
            int row = c >> 4, cc = c & 15;
            *(half8*)&w2s[row * H_STRIDE + cc * 8] = *(const half8*)&wt2g[row * 128 + cc * 8];
        }
        if (t < 128) {
            b0s[t] = *(const float*)(ws + WS_B0 + t * 4);
            b1s[t] = *(const float*)(ws + WS_B1 + t * 4);
        } else if (t < 192) {
            b2s[t - 128] = *(const float*)(ws + WS_B2 + (size_t)(t - 128) * 4);
        }
    }
    __syncthreads();
    // NOTE: no __syncthreads() inside the tile loop — weights are read-only and hc is
    // strictly per-wave, so waves free-run and self-pipeline across tiles.

    for (; tile < EDGE_TILES; tile += EDGE_GRID) {
        const int base = tile * 256 + wave * 32;

        // ---- gather z[s]+z[d]+b0, leaky -> A-frags for both 16-edge groups
        half8 a1[2][4];
        #pragma unroll
        for (int g = 0; g < 2; ++g) {
            const int ss = g ? s1 : s0, dd = g ? d1 : d0;
            const _Float16* zs = z + (size_t)ss * 128;
            const _Float16* zd = z + (size_t)dd * 128;
            half8 u[4], v[4];
            #pragma unroll
            for (int ks = 0; ks < 4; ++ks) {
                u[ks] = *(const half8*)(zs + ks * 32 + q * 8);
                v[ks] = *(const half8*)(zd + ks * 32 + q * 8);
            }
            #pragma unroll
            for (int ks = 0; ks < 4; ++ks) {
                floatx4 bA = *(const floatx4*)&b0s[ks * 32 + q * 8];
                floatx4 bB = *(const floatx4*)&b0s[ks * 32 + q * 8 + 4];
                #pragma unroll
                for (int j = 0; j < 4; ++j) {
                    float t0 = (float)u[ks][j]     + (float)v[ks][j]     + bA[j];
                    float t1 = (float)u[ks][4 + j] + (float)v[ks][4 + j] + bB[j];
                    a1[g][ks][j]     = (_Float16)leaky(t0);
                    a1[g][ks][4 + j] = (_Float16)leaky(t1);
                }
            }
        }

        // prefetch next tile's indices — latency hides under the MFMA phase below
        {
            const int nt = tile + EDGE_GRID;
            if (nt < EDGE_TILES) {
                const int rn = nt * 256 + wave * 32 + cl;
                s0 = ei[rn];      d0 = ei[N_EDGES + rn];
                s1 = ei[rn + 16]; d1 = ei[N_EDGES + rn + 16];
            }
        }

        floatx4 acc2[2][4];
        #pragma unroll
        for (int g = 0; g < 2; ++g)
            #pragma unroll
            for (int n2 = 0; n2 < 4; ++n2) acc2[g][n2] = (floatx4){0.f, 0.f, 0.f, 0.f};

        // layer 1 produces h in 32-col chunks (k-step of layer 2); each W-frag read
        // from LDS feeds TWO MFMAs (both edge groups) — halves LDS read traffic/edge
        #pragma unroll
        for (int ks = 0; ks < 4; ++ks) {
            #pragma unroll
            for (int nn = 0; nn < 2; ++nn) {
                const int n = ks * 2 + nn;
                floatx4 c0 = {0.f, 0.f, 0.f, 0.f}, c1 = {0.f, 0.f, 0.f, 0.f};
                #pragma unroll
                for (int kk = 0; kk < 4; ++kk) {
                    half8 b = *(const half8*)&w1s[(n * 16 + cl) * H_STRIDE + kk * 32 + q * 8];
                    c0 = __builtin_amdgcn_mfma_f32_16x16x32_f16(a1[0][kk], b, c0, 0, 0, 0);
                    c1 = __builtin_amdgcn_mfma_f32_16x16x32_f16(a1[1][kk], b, c1, 0, 0, 0);
                }
                const float bb = b1s[n * 16 + cl];
                #pragma unroll
                for (int rr = 0; rr < 4; ++rr) {   // C/D: col=lane&15, row=q*4+rr
                    hc[wave][0][(q * 4 + rr) * HC_STRIDE + nn * 16 + cl] = (_Float16)leaky(c0[rr] + bb);
                    hc[wave][1][(q * 4 + rr) * HC_STRIDE + nn * 16 + cl] = (_Float16)leaky(c1[rr] + bb);
                }
            }
            // C-layout -> A-layout round trip through the per-wave LDS chunk
            half8 a20 = *(const half8*)&hc[wave][0][cl * HC_STRIDE + q * 8];
            half8 a21 = *(const half8*)&hc[wave][1][cl * HC_STRIDE + q * 8];
            #pragma unroll
            for (int n2 = 0; n2 < 4; ++n2) {
                half8 b = *(const half8*)&w2s[(n2 * 16 + cl) * H_STRIDE + ks * 32 + q * 8];
                // SWAPPED operands: D is transposed -> lane holds 4 CONSECUTIVE output
                // features (n = n2*16 + q*4 + rr) for edge (base + g*16 + cl)
                acc2[0][n2] = __builtin_amdgcn_mfma_f32_16x16x32_f16(b, a20, acc2[0][n2], 0, 0, 0);
                acc2[1][n2] = __builtin_amdgcn_mfma_f32_16x16x32_f16(b, a21, acc2[1][n2], 0, 0, 0);
            }
        }

        // epilogue: register-direct float4 stores, nontemporal (write-once stream;
        // keeps L2 for the z gather table)
        #pragma unroll
        for (int n2 = 0; n2 < 4; ++n2) {
            floatx4 bb = *(const floatx4*)&b2s[n2 * 16 + q * 4];
            #pragma unroll
            for (int g = 0; g < 2; ++g) {
                floatx4 o;
                #pragma unroll
                for (int rr = 0; rr < 4; ++rr) o[rr] = leaky(acc2[g][n2][rr] + bb[rr]);
                __builtin_nontemporal_store(o,
                    (floatx4*)(out + (size_t)(base + g * 16 + cl) * 64 + n2 * 16 + q * 4));
            }
        }
    }
}

extern "C" void kernel_launch(void* const* d_in, const int* in_sizes, int n_in,
                              void* d_out, int out_size, void* d_ws, size_t ws_size,
                              hipStream_t stream) {
    const float* x  = (const float*)d_in[0];
    const int*   ei = (const int*)d_in[1];     // int inputs arrive as int32
    const float* W0 = (const float*)d_in[2];
    const float* b0 = (const float*)d_in[3];
    const float* W1 = (const float*)d_in[4];
    const float* b1 = (const float*)d_in[5];
    const float* W2 = (const float*)d_in[6];
    const float* b2 = (const float*)d_in[7];
    float* out = (float*)d_out;
    unsigned char* ws = (unsigned char*)d_ws;

    z_kernel<<<Z_BLOCKS + 1, 512, 0, stream>>>(x, W0, W1, W2, b0, b1, b2, ws);
    edge_kernel<<<EDGE_GRID, 512, 0, stream>>>(ei, ws, out);
}

// Round 2
// 276.053 us; speedup vs baseline: 1.6003x; 1.6003x over previous
//
#include <hip/hip_runtime.h>

typedef _Float16 half8  __attribute__((ext_vector_type(8)));
typedef float    floatx4 __attribute__((ext_vector_type(4)));

#define N_NODES 50000
#define N_EDGES 800000
#define SLOPE 0.05f

// ---- workspace layout (bytes) ----
// xh:  fp16 [N_NODES][64]   = fp16(x)           (gather table: 128 B/row, 6.4 MB)
// w0t: fp16 [128][64]       w0t[n][k] = W0[k][n]
// wt1: fp16 [128][128]      wt1[n][k] = W1[k][n]
// wt2: fp16 [64][128]       wt2[n][k] = W2[k][n]
// b0,b1,b2: fp32
#define WS_XH  0ull
#define WS_W0  (WS_XH + (size_t)N_NODES * 64 * 2)
#define WS_W1  (WS_W0 + 128 * 64 * 2)
#define WS_W2  (WS_W1 + 128 * 128 * 2)
#define WS_B0  (WS_W2 + 64 * 128 * 2)
#define WS_B1  (WS_B0 + 128 * 4)
#define WS_B2  (WS_B1 + 128 * 4)

#define HC_STRIDE 40            // 32 + 8 fp16 pad (proven round-1 exchange layout)
#define XCONV_BLOCKS 782        // ceil(50000*64 / (512*8))
#define PREP_BLOCKS (XCONV_BLOCKS + 65)

__device__ __forceinline__ float leaky(float t) { return t >= 0.f ? t : SLOPE * t; }

// ---------------- kernel 1: x->fp16 convert + weight transpose ----------------
__global__ void prep_kernel(const float* __restrict__ x,
                            const float* __restrict__ W0, const float* __restrict__ W1,
                            const float* __restrict__ W2, const float* __restrict__ b0,
                            const float* __restrict__ b1, const float* __restrict__ b2,
                            unsigned char* __restrict__ ws) {
    const int b = blockIdx.x;
    if (b < XCONV_BLOCKS) {                     // x [50000][64] fp32 -> xh fp16
        _Float16* xh = (_Float16*)(ws + WS_XH);
        const int i = (b * 512 + threadIdx.x) * 8;
        if (i < N_NODES * 64) {
            floatx4 u0 = *(const floatx4*)(x + i);
            floatx4 u1 = *(const floatx4*)(x + i + 4);
            half8 h;
            #pragma unroll
            for (int j = 0; j < 4; ++j) { h[j] = (_Float16)u0[j]; h[4 + j] = (_Float16)u1[j]; }
            *(half8*)(xh + i) = h;
        }
        return;
    }
    const int t = (b - XCONV_BLOCKS) * 512 + threadIdx.x;
    _Float16* w0t = (_Float16*)(ws + WS_W0);
    _Float16* wt1 = (_Float16*)(ws + WS_W1);
    _Float16* wt2 = (_Float16*)(ws + WS_W2);
    if (t < 8192) {                             // W0 [64][128] -> w0t[n][k]
        int k = t >> 7, n = t & 127;
        w0t[n * 64 + k] = (_Float16)W0[k * 128 + n];
    } else if (t < 24576) {                     // W1 [128][128] -> wt1[n][k]
        int i2 = t - 8192, k = i2 >> 7, n = i2 & 127;
        wt1[n * 128 + k] = (_Float16)W1[k * 128 + n];
    } else if (t < 32768) {                     // W2 [128][64] -> wt2[n][k]
        int i2 = t - 24576, k = i2 >> 6, n = i2 & 63;
        wt2[n * 128 + k] = (_Float16)W2[k * 64 + n];
    } else if (t < 33088) {
        int i2 = t - 32768;
        if (i2 < 128) ((float*)(ws + WS_B0))[i2] = b0[i2];
        else if (i2 < 256) ((float*)(ws + WS_B1))[i2 - 128] = b1[i2 - 128];
        else ((float*)(ws + WS_B2))[i2 - 256] = b2[i2 - 256];
    }
}

// ---------------- kernel 2: per-edge fused 3-layer MLP ----------------
// Non-persistent, self-balancing: 3125 blocks x 256 edges. 8 waves; each wave owns
// 32 edges (two 16-edge A-frag groups sharing every weight-fragment LDS read).
// Gather is xh (128 B/node, half of round-1's z at 256 B) and layer 0 is computed
// per edge by MFMA -- fabric fetch halves; MFMA pipe (7% util) absorbs the work.
__global__ __launch_bounds__(512, 4) void edge_kernel(const int* __restrict__ ei,
                                                      const unsigned char* __restrict__ ws,
                                                      float* __restrict__ out) {
    // all weight tiles unpadded, XOR-swizzled (half_idx ^= (row&7)<<3):
    // breaks the 128B/256B row-stride same-bank pattern on ds_read_b128
    __shared__ __align__(16) _Float16 w0s[128 * 64];          // 16384 B
    __shared__ __align__(16) _Float16 w1s[128 * 128];         // 32768 B
    __shared__ __align__(16) _Float16 w2s[64 * 128];          // 16384 B
    __shared__ __align__(16) _Float16 hc[8][16 * HC_STRIDE];  // 10240 B (per-wave, reused)
    __shared__ __align__(16) float b0s[128], b1s[128], b2s[64];
    // total 77056 B -> 2 blocks/CU

    const _Float16* __restrict__ xh  = (const _Float16*)(ws + WS_XH);
    const _Float16* __restrict__ w0g = (const _Float16*)(ws + WS_W0);
    const _Float16* __restrict__ w1g = (const _Float16*)(ws + WS_W1);
    const _Float16* __restrict__ w2g = (const _Float16*)(ws + WS_W2);

    const int wave = threadIdx.x >> 6, lane = threadIdx.x & 63;
    const int cl = lane & 15, q = lane >> 4;
    const int base = blockIdx.x * 256 + wave * 32;

    // indices + gather issued FIRST: HBM latency hides under weight staging
    const int r0 = base + cl;
    const int s0 = ei[r0], d0 = ei[N_EDGES + r0];
    const int s1 = ei[r0 + 16], d1 = ei[N_EDGES + r0 + 16];

    const _Float16* ps0 = xh + (size_t)s0 * 64 + q * 8;
    const _Float16* pd0 = xh + (size_t)d0 * 64 + q * 8;
    const _Float16* ps1 = xh + (size_t)s1 * 64 + q * 8;
    const _Float16* pd1 = xh + (size_t)d1 * 64 + q * 8;
    half8 us00 = *(const half8*)(ps0);  half8 us01 = *(const half8*)(ps0 + 32);
    half8 ud00 = *(const half8*)(pd0);  half8 ud01 = *(const half8*)(pd0 + 32);
    half8 us10 = *(const half8*)(ps1);  half8 us11 = *(const half8*)(ps1 + 32);
    half8 ud10 = *(const half8*)(pd1);  half8 ud11 = *(const half8*)(pd1 + 32);

    {   // stage swizzled weights (reads hit L2 -- weights hot in all XCD L2s)
        const int t = threadIdx.x;
        #pragma unroll
        for (int it = 0; it < 4; ++it) {
            int c = t + it * 512, row = c >> 4, cc = c & 15;
            int dst = (row * 128 + cc * 8) ^ ((row & 7) << 3);
            *(half8*)&w1s[dst] = *(const half8*)&w1g[row * 128 + cc * 8];
        }
        #pragma unroll
        for (int it = 0; it < 2; ++it) {
            int c = t + it * 512, row = c >> 4, cc = c & 15;
            int dst = (row * 128 + cc * 8) ^ ((row & 7) << 3);
            *(half8*)&w2s[dst] = *(const half8*)&w2g[row * 128 + cc * 8];
        }
        #pragma unroll
        for (int it = 0; it < 2; ++it) {
            int c = t + it * 512, row = c >> 3, cc = c & 7;
            int dst = (row * 64 + cc * 8) ^ ((row & 7) << 3);
            *(half8*)&w0s[dst] = *(const half8*)&w0g[row * 64 + cc * 8];
        }
        if (t < 128) { b0s[t] = *(const float*)(ws + WS_B0 + t * 4);
                       b1s[t] = *(const float*)(ws + WS_B1 + t * 4); }
        else if (t < 192) b2s[t - 128] = *(const float*)(ws + WS_B2 + (size_t)(t - 128) * 4);
    }
    __syncthreads();

    // e = xh[s] + xh[d] (fp16) directly as A-frags: A[m=cl edge][k = ks*32 + q*8 + j]
    half8 a0[2][2];
    a0[0][0] = us00 + ud00;  a0[0][1] = us01 + ud01;
    a0[1][0] = us10 + ud10;  a0[1][1] = us11 + ud11;

    const int swz = (cl & 7) << 3;
    _Float16* hw = &hc[wave][0];

    // ---- layer 0: h0 chunks n=2kk,2kk+1 -> hc round trip -> a1[g][kk] A-frags
    half8 a1[2][4];
    #pragma unroll
    for (int kk = 0; kk < 4; ++kk) {
        const int nA = 2 * kk, nB = 2 * kk + 1;
        half8 wA0 = *(const half8*)&w0s[((nA * 16 + cl) * 64 + q * 8) ^ swz];
        half8 wA1 = *(const half8*)&w0s[((nA * 16 + cl) * 64 + 32 + q * 8) ^ swz];
        half8 wB0 = *(const half8*)&w0s[((nB * 16 + cl) * 64 + q * 8) ^ swz];
        half8 wB1 = *(const half8*)&w0s[((nB * 16 + cl) * 64 + 32 + q * 8) ^ swz];
        const float bbA = b0s[nA * 16 + cl], bbB = b0s[nB * 16 + cl];
        #pragma unroll
        for (int g = 0; g < 2; ++g) {       // sequential hc reuse (per-wave, lgkm-ordered)
            floatx4 cA = {0.f, 0.f, 0.f, 0.f}, cB = {0.f, 0.f, 0.f, 0.f};
            cA = __builtin_amdgcn_mfma_f32_16x16x32_f16(a0[g][0], wA0, cA, 0, 0, 0);
            cA = __builtin_amdgcn_mfma_f32_16x16x32_f16(a0[g][1], wA1, cA, 0, 0, 0);
            cB = __builtin_amdgcn_mfma_f32_16x16x32_f16(a0[g][0], wB0, cB, 0, 0, 0);
            cB = __builtin_amdgcn_mfma_f32_16x16x32_f16(a0[g][1], wB1, cB, 0, 0, 0);
            #pragma unroll
            for (int rr = 0; rr < 4; ++rr) {   // C/D: row(edge)=q*4+rr, col=cl
                hw[(q * 4 + rr) * HC_STRIDE + cl]      = (_Float16)leaky(cA[rr] + bbA);
                hw[(q * 4 + rr) * HC_STRIDE + 16 + cl] = (_Float16)leaky(cB[rr] + bbB);
            }
            a1[g][kk] = *(const half8*)&hw[cl * HC_STRIDE + q * 8];
        }
    }

    // ---- layers 1+2, interleaved by 32-col k-chunks; weight frags shared by both groups
    floatx4 acc2[2][4];
    #pragma unroll
    for (int g = 0; g < 2; ++g)
        #pragma unroll
        for (int n2 = 0; n2 < 4; ++n2) acc2[g][n2] = (floatx4){0.f, 0.f, 0.f, 0.f};

    #pragma unroll
    for (int ks = 0; ks < 4; ++ks) {
        const int nA = 2 * ks, nB = 2 * ks + 1;
        floatx4 cA0 = {0.f,0.f,0.f,0.f}, cA1 = {0.f,0.f,0.f,0.f};
        floatx4 cB0 = {0.f,0.f,0.f,0.f}, cB1 = {0.f,0.f,0.f,0.f};
        #pragma unroll
        for (int kk = 0; kk < 4; ++kk) {
            half8 b = *(const half8*)&w1s[((nA * 16 + cl) * 128 + kk * 32 + q * 8) ^ swz];
            cA0 = __builtin_amdgcn_mfma_f32_16x16x32_f16(a1[0][kk], b, cA0, 0, 0, 0);
            cA1 = __builtin_amdgcn_mfma_f32_16x16x32_f16(a1[1][kk], b, cA1, 0, 0, 0);
        }
        #pragma unroll
        for (int kk = 0; kk < 4; ++kk) {
            half8 b = *(const half8*)&w1s[((nB * 16 + cl) * 128 + kk * 32 + q * 8) ^ swz];
            cB0 = __builtin_amdgcn_mfma_f32_16x16x32_f16(a1[0][kk], b, cB0, 0, 0, 0);
            cB1 = __builtin_amdgcn_mfma_f32_16x16x32_f16(a1[1][kk], b, cB1, 0, 0, 0);
        }
        const float bbA = b1s[nA * 16 + cl], bbB = b1s[nB * 16 + cl];
        half8 a2[2];
        #pragma unroll
        for (int g = 0; g < 2; ++g) {       // sequential hc reuse again
            const floatx4 cc0 = g ? cA1 : cA0;
            const floatx4 cc1 = g ? cB1 : cB0;
            #pragma unroll
            for (int rr = 0; rr < 4; ++rr) {
                hw[(q * 4 + rr) * HC_STRIDE + cl]      = (_Float16)leaky(cc0[rr] + bbA);
                hw[(q * 4 + rr) * HC_STRIDE + 16 + cl] = (_Float16)leaky(cc1[rr] + bbB);
            }
            a2[g] = *(const half8*)&hw[cl * HC_STRIDE + q * 8];
        }
        #pragma unroll
        for (int n2 = 0; n2 < 4; ++n2) {
            half8 b = *(const half8*)&w2s[((n2 * 16 + cl) * 128 + ks * 32 + q * 8) ^ swz];
            // swapped operands: lane holds 4 CONSECUTIVE output features for edge cl
            acc2[0][n2] = __builtin_amdgcn_mfma_f32_16x16x32_f16(b, a2[0], acc2[0][n2], 0, 0, 0);
            acc2[1][n2] = __builtin_amdgcn_mfma_f32_16x16x32_f16(b, a2[1], acc2[1][n2], 0, 0, 0);
        }
    }

    // epilogue: register-direct float4 stores, NORMAL (L2 write-combines the row)
    #pragma unroll
    for (int n2 = 0; n2 < 4; ++n2) {
        floatx4 bb = *(const floatx4*)&b2s[n2 * 16 + q * 4];
        #pragma unroll
        for (int g = 0; g < 2; ++g) {
            floatx4 o;
            #pragma unroll
            for (int rr = 0; rr < 4; ++rr) o[rr] = leaky(acc2[g][n2][rr] + bb[rr]);
            *(floatx4*)(out + (size_t)(base + g * 16 + cl) * 64 + n2 * 16 + q * 4) = o;
        }
    }
}

extern "C" void kernel_launch(void* const* d_in, const int* in_sizes, int n_in,
                              void* d_out, int out_size, void* d_ws, size_t ws_size,
                              hipStream_t stream) {
    const float* x  = (const float*)d_in[0];
    const int*   ei = (const int*)d_in[1];     // int inputs arrive as int32
    const float* W0 = (const float*)d_in[2];
    const float* b0 = (const float*)d_in[3];
    const float* W1 = (const float*)d_in[4];
    const float* b1 = (const float*)d_in[5];
    const float* W2 = (const float*)d_in[6];
    const float* b2 = (const float*)d_in[7];
    float* out = (float*)d_out;
    unsigned char* ws = (unsigned char*)d_ws;

    prep_kernel<<<PREP_BLOCKS, 512, 0, stream>>>(x, W0, W1, W2, b0, b1, b2, ws);
    edge_kernel<<<N_EDGES / 256, 512, 0, stream>>>(ei, ws, out);
}